// Round 1
// baseline (207.916 us; speedup 1.0000x reference)
//
#include <hip/hip_runtime.h>
#include <math.h>

#define NN 1024   // nodes
#define FD 64     // features
#define EE 65536  // edges
#define HD 32     // hidden

__device__ __forceinline__ float sigmoid_f(float z) {
  return 1.0f / (1.0f + expf(-z));
}

// ---------------------------------------------------------------------------
// Precompute per-node partial hidden activations:
//   pre[0*NN*HD + n*HD + h] = b1[h] + sum_f x[n][f] * W1[f][h]          (src block)
//   pre[1*NN*HD + n*HD + h] =         sum_f x[n][f] * W1[64+f][h]      (dst block)
// ---------------------------------------------------------------------------
__global__ __launch_bounds__(64) void pre_kernel(
    const float* __restrict__ x, const float* __restrict__ W1,
    const float* __restrict__ b1, float* __restrict__ pre) {
  const int n = blockIdx.x;
  const int t = threadIdx.x;
  const int h = t & 31;
  const int which = t >> 5;  // 0 = src block, 1 = dst block
  const float* xr = x + n * FD;
  const float* w = W1 + which * FD * HD + h;
  float acc = which ? 0.0f : b1[h];
#pragma unroll
  for (int f = 0; f < FD; ++f) acc = fmaf(xr[f], w[f * HD], acc);
  pre[which * (NN * HD) + n * HD + h] = acc;
}

// ---------------------------------------------------------------------------
// Full 4-block pair logit (used by edge kernel and the no-workspace fallback)
// ---------------------------------------------------------------------------
__device__ __forceinline__ float pair_logit_full(
    const float* __restrict__ xs, const float* __restrict__ xd,
    const float* __restrict__ W1, const float* __restrict__ b1,
    const float* __restrict__ W2, const float b2v) {
  float acc[HD];
#pragma unroll
  for (int h = 0; h < HD; ++h) acc[h] = b1[h];
#pragma unroll 1
  for (int c = 0; c < 8; ++c) {
    float sv[8], dv[8];
    const float4 s0 = ((const float4*)(xs + c * 8))[0];
    const float4 s1 = ((const float4*)(xs + c * 8))[1];
    const float4 d0 = ((const float4*)(xd + c * 8))[0];
    const float4 d1 = ((const float4*)(xd + c * 8))[1];
    sv[0] = s0.x; sv[1] = s0.y; sv[2] = s0.z; sv[3] = s0.w;
    sv[4] = s1.x; sv[5] = s1.y; sv[6] = s1.z; sv[7] = s1.w;
    dv[0] = d0.x; dv[1] = d0.y; dv[2] = d0.z; dv[3] = d0.w;
    dv[4] = d1.x; dv[5] = d1.y; dv[6] = d1.z; dv[7] = d1.w;
#pragma unroll
    for (int ff = 0; ff < 8; ++ff) {
      const int f = c * 8 + ff;
      const float a = sv[ff];
      const float b = dv[ff];
      const float ad = fabsf(a - b);
      const float pr = a * b;
      const float* w0 = W1 + f * HD;             // src block
      const float* w1 = W1 + (FD + f) * HD;      // dst block
      const float* w2 = W1 + (2 * FD + f) * HD;  // |diff| block
      const float* w3 = W1 + (3 * FD + f) * HD;  // prod block
#pragma unroll
      for (int h = 0; h < HD; ++h) {
        float t0 = fmaf(a, w0[h], acc[h]);
        t0 = fmaf(b, w1[h], t0);
        t0 = fmaf(ad, w2[h], t0);
        acc[h] = fmaf(pr, w3[h], t0);
      }
    }
  }
  float z = b2v;
#pragma unroll
  for (int h = 0; h < HD; ++h) z = fmaf(fmaxf(acc[h], 0.0f), W2[h], z);
  return z;
}

// ---------------------------------------------------------------------------
// Edge branch: one thread per edge, fp32 exact (actions are hard-thresholded)
// ---------------------------------------------------------------------------
__global__ __launch_bounds__(256) void edge_kernel(
    const float* __restrict__ x, const int* __restrict__ eidx,
    const float* __restrict__ W1, const float* __restrict__ b1,
    const float* __restrict__ W2, const float* __restrict__ b2,
    float* __restrict__ out) {
  const int e = blockIdx.x * 256 + threadIdx.x;
  // Detect whether edge_index arrived as int64 (little-endian: odd int32
  // words are the high halves == 0 for values in [0,1024)) or as int32.
  // Deterministic every call -> graph-capture safe.
  const bool is64 = (eidx[1] == 0) && (eidx[3] == 0) && (eidx[5] == 0);
  int s, d;
  if (is64) {
    s = eidx[2 * e];
    d = eidx[2 * (EE + e)];
  } else {
    s = eidx[e];
    d = eidx[EE + e];
  }
  const float z = pair_logit_full(x + (size_t)s * FD, x + (size_t)d * FD,
                                  W1, b1, W2, b2[0]);
  const float p = sigmoid_f(z);
  out[e] = p;                                // edge_probs
  out[EE + e] = (p > 0.4f) ? 1.0f : 0.0f;    // edge_actions
}

// ---------------------------------------------------------------------------
// Dense branch with per-node precompute: only |diff| and prod blocks remain.
// Block (64,4): wave-uniform i (xi broadcast), coalesced j stores.
// ---------------------------------------------------------------------------
__global__ __launch_bounds__(256) void dense_pre_kernel(
    const float* __restrict__ x, const float* __restrict__ W1,
    const float* __restrict__ W2, const float* __restrict__ b2,
    const float* __restrict__ pre, float* __restrict__ outP) {
  const int j = blockIdx.x * 64 + threadIdx.x;
  const int i = blockIdx.y * 4 + threadIdx.y;
  const float* ps = pre + (size_t)i * HD;
  const float* pd = pre + (size_t)NN * HD + (size_t)j * HD;
  float acc[HD];
#pragma unroll
  for (int h = 0; h < HD; ++h) acc[h] = ps[h] + pd[h];
  const float* xi = x + (size_t)i * FD;
  const float* xj = x + (size_t)j * FD;
  const float* W1c = W1 + 2 * FD * HD;
  const float* W1d = W1 + 3 * FD * HD;
#pragma unroll 1
  for (int c = 0; c < 4; ++c) {
    float iv[16], jv[16];
#pragma unroll
    for (int q = 0; q < 4; ++q) {
      const float4 u = ((const float4*)(xi + c * 16))[q];
      iv[q * 4 + 0] = u.x; iv[q * 4 + 1] = u.y;
      iv[q * 4 + 2] = u.z; iv[q * 4 + 3] = u.w;
      const float4 v = ((const float4*)(xj + c * 16))[q];
      jv[q * 4 + 0] = v.x; jv[q * 4 + 1] = v.y;
      jv[q * 4 + 2] = v.z; jv[q * 4 + 3] = v.w;
    }
#pragma unroll
    for (int ff = 0; ff < 16; ++ff) {
      const int f = c * 16 + ff;
      const float a = iv[ff];
      const float b = jv[ff];
      const float ad = fabsf(a - b);
      const float pr = a * b;
      const float* wc = W1c + f * HD;
      const float* wd = W1d + f * HD;
#pragma unroll
      for (int h = 0; h < HD; ++h) {
        acc[h] = fmaf(pr, wd[h], fmaf(ad, wc[h], acc[h]));
      }
    }
  }
  float z = b2[0];
#pragma unroll
  for (int h = 0; h < HD; ++h) z = fmaf(fmaxf(acc[h], 0.0f), W2[h], z);
  outP[(size_t)i * NN + j] = sigmoid_f(z);
}

// Fallback if workspace is too small: full 4-block compute per pair.
__global__ __launch_bounds__(256) void dense_full_kernel(
    const float* __restrict__ x, const float* __restrict__ W1,
    const float* __restrict__ b1, const float* __restrict__ W2,
    const float* __restrict__ b2, float* __restrict__ outP) {
  const int j = blockIdx.x * 64 + threadIdx.x;
  const int i = blockIdx.y * 4 + threadIdx.y;
  const float z = pair_logit_full(x + (size_t)i * FD, x + (size_t)j * FD,
                                  W1, b1, W2, b2[0]);
  outP[(size_t)i * NN + j] = sigmoid_f(z);
}

extern "C" void kernel_launch(void* const* d_in, const int* in_sizes, int n_in,
                              void* d_out, int out_size, void* d_ws, size_t ws_size,
                              hipStream_t stream) {
  const float* x  = (const float*)d_in[0];
  const int*  ei  = (const int*)d_in[1];   // edge_index (int64-vs-int32 auto-detected)
  // d_in[2] = edge_index_global: unused by the reference computation
  const float* W1 = (const float*)d_in[3];
  const float* b1 = (const float*)d_in[4];
  const float* W2 = (const float*)d_in[5];
  const float* b2 = (const float*)d_in[6];
  float* out  = (float*)d_out;           // [0,EE): probs, [EE,2EE): actions
  float* outP = out + 2 * EE;            // [2EE, 2EE+NN*NN): P

  // Edge branch: 65536 threads
  edge_kernel<<<EE / 256, 256, 0, stream>>>(x, ei, W1, b1, W2, b2, out);

  const size_t pre_bytes = (size_t)2 * NN * HD * sizeof(float);
  if (ws_size >= pre_bytes) {
    float* pre = (float*)d_ws;
    pre_kernel<<<NN, 64, 0, stream>>>(x, W1, b1, pre);
    dense_pre_kernel<<<dim3(NN / 64, NN / 4), dim3(64, 4), 0, stream>>>(
        x, W1, W2, b2, pre, outP);
  } else {
    dense_full_kernel<<<dim3(NN / 64, NN / 4), dim3(64, 4), 0, stream>>>(
        x, W1, b1, W2, b2, outP);
  }
}

// Round 2
// 137.961 us; speedup vs baseline: 1.5071x; 1.5071x over previous
//
#include <hip/hip_runtime.h>
#include <hip/hip_bf16.h>
#include <math.h>

#define NN 1024   // nodes
#define FD 64     // features
#define EE 65536  // edges
#define HD 32     // hidden

typedef __attribute__((ext_vector_type(8))) short short8;
typedef __attribute__((ext_vector_type(4))) float floatx4;

__device__ __forceinline__ float sigmoid_f(float z) {
  return 1.0f / (1.0f + expf(-z));
}
__device__ __forceinline__ float sigmoid_fast(float z) {
  return 1.0f / (1.0f + __expf(-z));
}

// pack two fp32 -> packed 2x bf16 (truncation) in one v_perm_b32
__device__ __forceinline__ unsigned pack_bf16_trunc(float hi, float lo) {
  unsigned a = __builtin_bit_cast(unsigned, hi);
  unsigned b = __builtin_bit_cast(unsigned, lo);
  // D.b[0:1] = S1.b[2:3] (lo high half), D.b[2:3] = S0.b[2:3] (hi high half)
  return __builtin_amdgcn_perm(a, b, 0x07060302u);
}

// ---------------------------------------------------------------------------
// Pre-pass: per-node partial hidden activations (blocks 0,1 of W1) + bf16
// transposed copy of W1 blocks 2,3 (Wt[h][k], k=0..63 |diff|, 64..127 prod).
// ---------------------------------------------------------------------------
__global__ __launch_bounds__(64) void pre_kernel2(
    const float* __restrict__ x, const float* __restrict__ W1,
    const float* __restrict__ b1, float* __restrict__ pre,
    short* __restrict__ Wt) {
  const int blk = blockIdx.x;
  const int t = threadIdx.x;
  if (blk < NN) {
    const int h = t & 31;
    const int which = t >> 5;  // 0 = src block, 1 = dst block
    const float* xr = x + blk * FD;
    const float* w = W1 + which * FD * HD + h;
    float acc = which ? 0.0f : b1[h];
#pragma unroll
    for (int f = 0; f < FD; ++f) acc = fmaf(xr[f], w[f * HD], acc);
    pre[which * (NN * HD) + blk * HD + h] = acc;
  } else {
    // Wt[h][k] = bf16(W1[(2 + k/64)*64 + (k%64)][h]), RNE
    const int h = t >> 1;
    const int k0 = (t & 1) * 64;
    for (int kk = 0; kk < 64; ++kk) {
      const int k = k0 + kk;
      const int f = k & 63;
      const int b = 2 + (k >> 6);
      const float v = W1[(b * FD + f) * HD + h];
      __hip_bfloat16 hb = __float2bfloat16(v);
      Wt[h * 128 + k] = __builtin_bit_cast(short, hb);
    }
  }
}

// ---------------------------------------------------------------------------
// Dense branch, MFMA: per wave a 16-j tile; loop over 16 i's. For each (i,
// j-tile): A = features [16 pairs x 128 k] built in-register, B = Wt frags
// (hoisted), C init = pre_s[i][h] + pre_d[j][h]. Epilogue: relu, dot W2,
// butterfly-reduce, sigmoid, store.
// ---------------------------------------------------------------------------
__global__ __launch_bounds__(256, 3) void dense_mfma_kernel(
    const float* __restrict__ x, const float* __restrict__ pre,
    const short* __restrict__ Wt, const float* __restrict__ W2,
    const float* __restrict__ b2, float* __restrict__ outP) {
  const int lane = threadIdx.x & 63;
  const int w = threadIdx.x >> 6;
  const int q = lane >> 4;   // quad
  const int c = lane & 15;   // col / pair-in-tile
  const int j0 = blockIdx.x * 64 + w * 16;
  const int i0 = blockIdx.y * 16;

  // B fragments: [n-tile][k-step], element j = Wt[n*16+c][s*32+q*8+j]
  short8 Bf[2][4];
#pragma unroll
  for (int n = 0; n < 2; ++n)
#pragma unroll
    for (int s = 0; s < 4; ++s)
      Bf[n][s] = *(const short8*)(Wt + (n * 16 + c) * 128 + s * 32 + q * 8);

  // xj fragment: pair j0+c, f in [q*8,q*8+8) and [32+q*8, 32+q*8+8)
  const float* xj = x + (size_t)(j0 + c) * FD;
  const floatx4 xjA0 = *(const floatx4*)(xj + q * 8);
  const floatx4 xjA1 = *(const floatx4*)(xj + q * 8 + 4);
  const floatx4 xjB0 = *(const floatx4*)(xj + 32 + q * 8);
  const floatx4 xjB1 = *(const floatx4*)(xj + 32 + q * 8 + 4);

  // pre_d for rows m = q*4+r (tile0: h=c, tile1: h=16+c)
  float pdA[4], pdB[4];
#pragma unroll
  for (int r = 0; r < 4; ++r) {
    pdA[r] = pre[NN * HD + (j0 + q * 4 + r) * HD + c];
    pdB[r] = pre[NN * HD + (j0 + q * 4 + r) * HD + 16 + c];
  }
  const float w2a = W2[c], w2b = W2[16 + c];
  const float b2v = b2[0];

  for (int i = i0; i < i0 + 16; ++i) {
    const float* xi = x + (size_t)i * FD;
    const floatx4 xiA0 = *(const floatx4*)(xi + q * 8);
    const floatx4 xiA1 = *(const floatx4*)(xi + q * 8 + 4);
    const floatx4 xiB0 = *(const floatx4*)(xi + 32 + q * 8);
    const floatx4 xiB1 = *(const floatx4*)(xi + 32 + q * 8 + 4);
    const float psa = pre[i * HD + c];
    const float psb = pre[i * HD + 16 + c];

    floatx4 acc0, acc1;
#pragma unroll
    for (int r = 0; r < 4; ++r) {
      acc0[r] = psa + pdA[r];
      acc1[r] = psb + pdB[r];
    }

    // features: ad = |xi-xj|, pr = xi*xj for this lane's 16 f positions
    float adA[8], prA[8], adB[8], prB[8];
#pragma unroll
    for (int t = 0; t < 4; ++t) {
      { const float a = xiA0[t], b = xjA0[t];
        adA[t] = fabsf(a - b); prA[t] = a * b; }
      { const float a = xiA1[t], b = xjA1[t];
        adA[4 + t] = fabsf(a - b); prA[4 + t] = a * b; }
      { const float a = xiB0[t], b = xjB0[t];
        adB[t] = fabsf(a - b); prB[t] = a * b; }
      { const float a = xiB1[t], b = xjB1[t];
        adB[4 + t] = fabsf(a - b); prB[4 + t] = a * b; }
    }
    union { unsigned u[4]; short8 v; } fs0, fs1, fs2, fs3;
#pragma unroll
    for (int t = 0; t < 4; ++t) {
      fs0.u[t] = pack_bf16_trunc(adA[2 * t + 1], adA[2 * t]);  // k-step 0: ad f[0,32)
      fs1.u[t] = pack_bf16_trunc(adB[2 * t + 1], adB[2 * t]);  // k-step 1: ad f[32,64)
      fs2.u[t] = pack_bf16_trunc(prA[2 * t + 1], prA[2 * t]);  // k-step 2: pr f[0,32)
      fs3.u[t] = pack_bf16_trunc(prB[2 * t + 1], prB[2 * t]);  // k-step 3: pr f[32,64)
    }

    acc0 = __builtin_amdgcn_mfma_f32_16x16x32_bf16(fs0.v, Bf[0][0], acc0, 0, 0, 0);
    acc1 = __builtin_amdgcn_mfma_f32_16x16x32_bf16(fs0.v, Bf[1][0], acc1, 0, 0, 0);
    acc0 = __builtin_amdgcn_mfma_f32_16x16x32_bf16(fs1.v, Bf[0][1], acc0, 0, 0, 0);
    acc1 = __builtin_amdgcn_mfma_f32_16x16x32_bf16(fs1.v, Bf[1][1], acc1, 0, 0, 0);
    acc0 = __builtin_amdgcn_mfma_f32_16x16x32_bf16(fs2.v, Bf[0][2], acc0, 0, 0, 0);
    acc1 = __builtin_amdgcn_mfma_f32_16x16x32_bf16(fs2.v, Bf[1][2], acc1, 0, 0, 0);
    acc0 = __builtin_amdgcn_mfma_f32_16x16x32_bf16(fs3.v, Bf[0][3], acc0, 0, 0, 0);
    acc1 = __builtin_amdgcn_mfma_f32_16x16x32_bf16(fs3.v, Bf[1][3], acc1, 0, 0, 0);

    // epilogue: z[m] = b2 + sum_h relu(H[m][h]) * W2[h]
    float tr[4];
#pragma unroll
    for (int r = 0; r < 4; ++r) {
      tr[r] = fmaxf(acc0[r], 0.0f) * w2a;
      tr[r] = fmaf(fmaxf(acc1[r], 0.0f), w2b, tr[r]);
#pragma unroll
      for (int m = 1; m <= 8; m <<= 1) tr[r] += __shfl_xor(tr[r], m);
    }
    float zs = tr[0];
    zs = (c == 1) ? tr[1] : zs;
    zs = (c == 2) ? tr[2] : zs;
    zs = (c == 3) ? tr[3] : zs;
    if (c < 4) {
      outP[(size_t)i * NN + j0 + q * 4 + c] = sigmoid_fast(zs + b2v);
    }
  }
}

// ---------------------------------------------------------------------------
// Edge branch, fp32 exact: one wave per edge iteration. lane = (h, k-half).
// W1cd columns cached in VGPRs (64/lane), amortized over 16 edges/wave.
// ---------------------------------------------------------------------------
__global__ __launch_bounds__(256, 3) void edge_kernel2(
    const float* __restrict__ x, const int* __restrict__ eidx,
    const float* __restrict__ W1, const float* __restrict__ pre,
    const float* __restrict__ W2, const float* __restrict__ b2,
    float* __restrict__ out) {
  const int lane = threadIdx.x & 63;
  const int h = lane & 31;
  const int kh = lane >> 5;
  const int wid = blockIdx.x * 4 + (threadIdx.x >> 6);
  const int NW = gridDim.x * 4;

  float wc[32], wd[32];
#pragma unroll
  for (int f = 0; f < 32; ++f) {
    wc[f] = W1[(2 * FD + kh * 32 + f) * HD + h];
    wd[f] = W1[(3 * FD + kh * 32 + f) * HD + h];
  }
  const float w2h = W2[h];
  const float b2v = b2[0];
  const bool is64 = (eidx[1] == 0) && (eidx[3] == 0) && (eidx[5] == 0);

  for (int e = wid; e < EE; e += NW) {
    int s, d;
    if (is64) {
      s = eidx[2 * e];
      d = eidx[2 * (EE + e)];
    } else {
      s = eidx[e];
      d = eidx[EE + e];
    }
    const float* xs = x + (size_t)s * FD + kh * 32;
    const float* xd = x + (size_t)d * FD + kh * 32;
    float acc = 0.0f;
#pragma unroll
    for (int u = 0; u < 8; ++u) {
      const floatx4 a = *(const floatx4*)(xs + u * 4);
      const floatx4 b = *(const floatx4*)(xd + u * 4);
#pragma unroll
      for (int t = 0; t < 4; ++t) {
        const float df = fabsf(a[t] - b[t]);
        const float pr = a[t] * b[t];
        acc = fmaf(df, wc[u * 4 + t], acc);
        acc = fmaf(pr, wd[u * 4 + t], acc);
      }
    }
    acc += __shfl_xor(acc, 32);  // combine k-halves
    const float hv = acc + pre[s * HD + h] + pre[NN * HD + d * HD + h];
    float rv = fmaxf(hv, 0.0f) * w2h;
#pragma unroll
    for (int m = 1; m <= 16; m <<= 1) rv += __shfl_xor(rv, m);
    const float p = sigmoid_f(rv + b2v);
    if (lane == 0) {
      out[e] = p;
      out[EE + e] = (p > 0.4f) ? 1.0f : 0.0f;
    }
  }
}

// ---------------------------------------------------------------------------
// Fallbacks (no-workspace path) — round-1 kernels, kept for safety.
// ---------------------------------------------------------------------------
__device__ __forceinline__ float pair_logit_full(
    const float* __restrict__ xs, const float* __restrict__ xd,
    const float* __restrict__ W1, const float* __restrict__ b1,
    const float* __restrict__ W2, const float b2v) {
  float acc[HD];
#pragma unroll
  for (int h = 0; h < HD; ++h) acc[h] = b1[h];
#pragma unroll 1
  for (int c = 0; c < 8; ++c) {
    float sv[8], dv[8];
#pragma unroll
    for (int t = 0; t < 4; ++t) {
      sv[t] = xs[c * 8 + t]; sv[4 + t] = xs[c * 8 + 4 + t];
      dv[t] = xd[c * 8 + t]; dv[4 + t] = xd[c * 8 + 4 + t];
    }
#pragma unroll
    for (int ff = 0; ff < 8; ++ff) {
      const int f = c * 8 + ff;
      const float a = sv[ff], b = dv[ff];
      const float ad = fabsf(a - b), pr = a * b;
#pragma unroll
      for (int h = 0; h < HD; ++h) {
        float t0 = fmaf(a, W1[f * HD + h], acc[h]);
        t0 = fmaf(b, W1[(FD + f) * HD + h], t0);
        t0 = fmaf(ad, W1[(2 * FD + f) * HD + h], t0);
        acc[h] = fmaf(pr, W1[(3 * FD + f) * HD + h], t0);
      }
    }
  }
  float z = b2v;
#pragma unroll
  for (int h = 0; h < HD; ++h) z = fmaf(fmaxf(acc[h], 0.0f), W2[h], z);
  return z;
}

__global__ __launch_bounds__(256) void edge_kernel_fb(
    const float* __restrict__ x, const int* __restrict__ eidx,
    const float* __restrict__ W1, const float* __restrict__ b1,
    const float* __restrict__ W2, const float* __restrict__ b2,
    float* __restrict__ out) {
  const int e = blockIdx.x * 256 + threadIdx.x;
  const bool is64 = (eidx[1] == 0) && (eidx[3] == 0) && (eidx[5] == 0);
  int s, d;
  if (is64) { s = eidx[2 * e]; d = eidx[2 * (EE + e)]; }
  else { s = eidx[e]; d = eidx[EE + e]; }
  const float z = pair_logit_full(x + (size_t)s * FD, x + (size_t)d * FD,
                                  W1, b1, W2, b2[0]);
  const float p = sigmoid_f(z);
  out[e] = p;
  out[EE + e] = (p > 0.4f) ? 1.0f : 0.0f;
}

__global__ __launch_bounds__(256) void dense_full_fb(
    const float* __restrict__ x, const float* __restrict__ W1,
    const float* __restrict__ b1, const float* __restrict__ W2,
    const float* __restrict__ b2, float* __restrict__ outP) {
  const int j = blockIdx.x * 64 + threadIdx.x % 64;
  const int i = blockIdx.y * 4 + threadIdx.x / 64;
  const float z = pair_logit_full(x + (size_t)i * FD, x + (size_t)j * FD,
                                  W1, b1, W2, b2[0]);
  outP[(size_t)i * NN + j] = sigmoid_f(z);
}

extern "C" void kernel_launch(void* const* d_in, const int* in_sizes, int n_in,
                              void* d_out, int out_size, void* d_ws, size_t ws_size,
                              hipStream_t stream) {
  const float* x  = (const float*)d_in[0];
  const int*  ei  = (const int*)d_in[1];
  const float* W1 = (const float*)d_in[3];
  const float* b1 = (const float*)d_in[4];
  const float* W2 = (const float*)d_in[5];
  const float* b2 = (const float*)d_in[6];
  float* out  = (float*)d_out;
  float* outP = out + 2 * EE;

  const size_t need = (size_t)2 * NN * HD * sizeof(float) + 32 * 128 * sizeof(short);
  if (ws_size >= need) {
    float* pre = (float*)d_ws;
    short* Wt = (short*)(pre + 2 * NN * HD);
    pre_kernel2<<<NN + 1, 64, 0, stream>>>(x, W1, b1, pre, Wt);
    edge_kernel2<<<1024, 256, 0, stream>>>(x, ei, W1, pre, W2, b2, out);
    dense_mfma_kernel<<<dim3(16, 64), dim3(256), 0, stream>>>(
        x, pre, Wt, W2, b2, outP);
  } else {
    edge_kernel_fb<<<EE / 256, 256, 0, stream>>>(x, ei, W1, b1, W2, b2, out);
    dense_full_fb<<<dim3(NN / 64, NN / 4), dim3(64, 4), 0, stream>>>(
        x, W1, b1, W2, b2, outP);
  }
}

// Round 3
// 110.794 us; speedup vs baseline: 1.8766x; 1.2452x over previous
//
#include <hip/hip_runtime.h>
#include <hip/hip_bf16.h>
#include <math.h>

#define NN 1024   // nodes
#define FD 64     // features
#define EE 65536  // edges
#define HD 32     // hidden

typedef __attribute__((ext_vector_type(8))) short short8;
typedef __attribute__((ext_vector_type(4))) float floatx4;

__device__ __forceinline__ float sigmoid_f(float z) {
  return 1.0f / (1.0f + expf(-z));
}
__device__ __forceinline__ float sigmoid_fast(float z) {
  return 1.0f / (1.0f + __expf(-z));
}

// pack two fp32 -> packed 2x bf16 (truncation) in one v_perm_b32
// low short = lo's high half, high short = hi's high half
__device__ __forceinline__ unsigned pack_bf16_trunc(float hi, float lo) {
  unsigned a = __builtin_bit_cast(unsigned, hi);
  unsigned b = __builtin_bit_cast(unsigned, lo);
  return __builtin_amdgcn_perm(a, b, 0x07060302u);
}

// single-level bf16-trunc pack of 8 floats -> short8 (element t = v[t])
__device__ __forceinline__ short8 pack8(const float* v) {
  union { unsigned u[4]; short8 s; } p;
#pragma unroll
  for (int t = 0; t < 4; ++t) p.u[t] = pack_bf16_trunc(v[2 * t + 1], v[2 * t]);
  return p.s;
}

struct Frag3 { short8 a0, a1, a2; };

// 3-way bf16 split (truncation) of 8 fp32 values, packed into 3 A-fragments.
// v = a0 + a1 + a2 + eps, |eps| <= ~2^-23 |v|; all residual subtractions exact.
__device__ __forceinline__ Frag3 split_pack(const float* v) {
  float r[8], r2[8];
#pragma unroll
  for (int t = 0; t < 8; ++t) {
    const unsigned uv = __builtin_bit_cast(unsigned, v[t]);
    const float f0 = __builtin_bit_cast(float, uv & 0xFFFF0000u);
    const float rr = v[t] - f0;
    const unsigned ur = __builtin_bit_cast(unsigned, rr);
    const float f1 = __builtin_bit_cast(float, ur & 0xFFFF0000u);
    r[t] = rr;
    r2[t] = rr - f1;
  }
  Frag3 f;
  f.a0 = pack8(v);
  f.a1 = pack8(r);
  f.a2 = pack8(r2);
  return f;
}

// ---------------------------------------------------------------------------
// Pre-pass:
//  blocks 0..255 : pre[which][node][h] = (which?0:b1[h]) + x[node] @ W1-block(which)
//  block 256     : Wt0/1/2[h*128+k] = 3-way bf16 split of W1[(2+k/64)*64+(k%64)][h]
// ---------------------------------------------------------------------------
__global__ __launch_bounds__(256) void pre_kernel3(
    const float* __restrict__ x, const float* __restrict__ W1,
    const float* __restrict__ b1, float* __restrict__ pre,
    short* __restrict__ Wt0, short* __restrict__ Wt1, short* __restrict__ Wt2) {
  const int blk = blockIdx.x;
  const int t = threadIdx.x;
  if (blk < 256) {
    const int node = blk * 4 + (t >> 6);
    const int which = (t >> 5) & 1;
    const int h = t & 31;
    const float* xr = x + node * FD;
    const float* wp = W1 + which * FD * HD + h;
    float acc = which ? 0.0f : b1[h];
#pragma unroll
    for (int f = 0; f < FD; ++f) acc = fmaf(xr[f], wp[f * HD], acc);
    pre[which * (NN * HD) + node * HD + h] = acc;
  } else {
    for (int idx = t; idx < 32 * 128; idx += 256) {
      const int h = idx >> 7;
      const int k = idx & 127;
      const int f = k & 63;
      const int b = 2 + (k >> 6);
      const float v = W1[(b * FD + f) * HD + h];
      const unsigned uv = __builtin_bit_cast(unsigned, v);
      const unsigned u0 = uv & 0xFFFF0000u;
      const float f0 = __builtin_bit_cast(float, u0);
      const float r = v - f0;
      const unsigned u1 = __builtin_bit_cast(unsigned, r) & 0xFFFF0000u;
      const float f1 = __builtin_bit_cast(float, u1);
      const float r2 = r - f1;
      const unsigned u2 = __builtin_bit_cast(unsigned, r2) & 0xFFFF0000u;
      Wt0[idx] = (short)(u0 >> 16);
      Wt1[idx] = (short)(u1 >> 16);
      Wt2[idx] = (short)(u2 >> 16);
    }
  }
}

// ---------------------------------------------------------------------------
// Edge branch via split-MFMA (fp32-accurate): one 16-edge tile per wave.
// A = pair features (gathered rows), 3-way split; B = Wt splits; 6 products
// with combined magnitude >= 2^-24 kept -> logit error ~1e-6.
// ---------------------------------------------------------------------------
__device__ __forceinline__ void edge_chunk(
    const float* feat, const short* __restrict__ Wt0,
    const short* __restrict__ Wt1, const short* __restrict__ Wt2,
    int c, int q, int kc, floatx4& acc0, floatx4& acc1) {
  const Frag3 A = split_pack(feat);
  const int off0 = c * 128 + kc * 32 + q * 8;
  const int off1 = (16 + c) * 128 + kc * 32 + q * 8;
  const short8 B00 = *(const short8*)(Wt0 + off0);
  const short8 B01 = *(const short8*)(Wt1 + off0);
  const short8 B02 = *(const short8*)(Wt2 + off0);
  const short8 B10 = *(const short8*)(Wt0 + off1);
  const short8 B11 = *(const short8*)(Wt1 + off1);
  const short8 B12 = *(const short8*)(Wt2 + off1);
  acc0 = __builtin_amdgcn_mfma_f32_16x16x32_bf16(A.a0, B00, acc0, 0, 0, 0);
  acc0 = __builtin_amdgcn_mfma_f32_16x16x32_bf16(A.a0, B01, acc0, 0, 0, 0);
  acc0 = __builtin_amdgcn_mfma_f32_16x16x32_bf16(A.a0, B02, acc0, 0, 0, 0);
  acc0 = __builtin_amdgcn_mfma_f32_16x16x32_bf16(A.a1, B00, acc0, 0, 0, 0);
  acc0 = __builtin_amdgcn_mfma_f32_16x16x32_bf16(A.a1, B01, acc0, 0, 0, 0);
  acc0 = __builtin_amdgcn_mfma_f32_16x16x32_bf16(A.a2, B00, acc0, 0, 0, 0);
  acc1 = __builtin_amdgcn_mfma_f32_16x16x32_bf16(A.a0, B10, acc1, 0, 0, 0);
  acc1 = __builtin_amdgcn_mfma_f32_16x16x32_bf16(A.a0, B11, acc1, 0, 0, 0);
  acc1 = __builtin_amdgcn_mfma_f32_16x16x32_bf16(A.a0, B12, acc1, 0, 0, 0);
  acc1 = __builtin_amdgcn_mfma_f32_16x16x32_bf16(A.a1, B10, acc1, 0, 0, 0);
  acc1 = __builtin_amdgcn_mfma_f32_16x16x32_bf16(A.a1, B11, acc1, 0, 0, 0);
  acc1 = __builtin_amdgcn_mfma_f32_16x16x32_bf16(A.a2, B10, acc1, 0, 0, 0);
}

__global__ __launch_bounds__(256, 2) void edge_mfma_kernel(
    const float* __restrict__ x, const int* __restrict__ eidx,
    const float* __restrict__ pre, const short* __restrict__ Wt0,
    const short* __restrict__ Wt1, const short* __restrict__ Wt2,
    const float* __restrict__ W2, const float* __restrict__ b2,
    float* __restrict__ out) {
  const int lane = threadIdx.x & 63;
  const int q = lane >> 4;
  const int c = lane & 15;
  const int e0 = (blockIdx.x * 4 + (threadIdx.x >> 6)) * 16;

  const bool is64 = (eidx[1] == 0) && (eidx[3] == 0) && (eidx[5] == 0);
  int s_c, d_c;
  if (is64) {
    s_c = eidx[2 * (e0 + c)];
    d_c = eidx[2 * (EE + e0 + c)];
  } else {
    s_c = eidx[e0 + c];
    d_c = eidx[EE + e0 + c];
  }
  const float* xs = x + (size_t)s_c * FD;
  const float* xd = x + (size_t)d_c * FD;

  // C init: rows m=q*4+r are edges e0+q*4+r; gather their pre rows
  floatx4 acc0, acc1;
#pragma unroll
  for (int r = 0; r < 4; ++r) {
    const int m = q * 4 + r;
    const int sm = __shfl(s_c, m);
    const int dm = __shfl(d_c, m);
    acc0[r] = pre[sm * HD + c] + pre[NN * HD + dm * HD + c];
    acc1[r] = pre[sm * HD + 16 + c] + pre[NN * HD + dm * HD + 16 + c];
  }

  // half A: f in [q*8, q*8+8)
  {
    const floatx4 s0 = *(const floatx4*)(xs + q * 8);
    const floatx4 s1 = *(const floatx4*)(xs + q * 8 + 4);
    const floatx4 d0 = *(const floatx4*)(xd + q * 8);
    const floatx4 d1 = *(const floatx4*)(xd + q * 8 + 4);
    float ad[8], pr[8];
#pragma unroll
    for (int t = 0; t < 4; ++t) {
      ad[t] = fabsf(s0[t] - d0[t]);     pr[t] = s0[t] * d0[t];
      ad[4 + t] = fabsf(s1[t] - d1[t]); pr[4 + t] = s1[t] * d1[t];
    }
    edge_chunk(ad, Wt0, Wt1, Wt2, c, q, 0, acc0, acc1);
    edge_chunk(pr, Wt0, Wt1, Wt2, c, q, 2, acc0, acc1);
  }
  // half B: f in [32+q*8, 32+q*8+8)
  {
    const floatx4 s0 = *(const floatx4*)(xs + 32 + q * 8);
    const floatx4 s1 = *(const floatx4*)(xs + 32 + q * 8 + 4);
    const floatx4 d0 = *(const floatx4*)(xd + 32 + q * 8);
    const floatx4 d1 = *(const floatx4*)(xd + 32 + q * 8 + 4);
    float ad[8], pr[8];
#pragma unroll
    for (int t = 0; t < 4; ++t) {
      ad[t] = fabsf(s0[t] - d0[t]);     pr[t] = s0[t] * d0[t];
      ad[4 + t] = fabsf(s1[t] - d1[t]); pr[4 + t] = s1[t] * d1[t];
    }
    edge_chunk(ad, Wt0, Wt1, Wt2, c, q, 1, acc0, acc1);
    edge_chunk(pr, Wt0, Wt1, Wt2, c, q, 3, acc0, acc1);
  }

  // epilogue: z[m] = b2 + sum_h relu(H[m][h]) * W2[h]
  const float w2a = W2[c], w2b = W2[16 + c];
  const float b2v = b2[0];
  float tr[4];
#pragma unroll
  for (int r = 0; r < 4; ++r) {
    tr[r] = fmaxf(acc0[r], 0.0f) * w2a;
    tr[r] = fmaf(fmaxf(acc1[r], 0.0f), w2b, tr[r]);
#pragma unroll
    for (int m = 1; m <= 8; m <<= 1) tr[r] += __shfl_xor(tr[r], m);
  }
  float zs = tr[0];
  zs = (c == 1) ? tr[1] : zs;
  zs = (c == 2) ? tr[2] : zs;
  zs = (c == 3) ? tr[3] : zs;
  if (c < 4) {
    const int e = e0 + q * 4 + c;
    const float z = zs + b2v;
    out[e] = sigmoid_f(z);
    // p > 0.4  <=>  z > ln(0.4/0.6); monotone-exact, avoids sigmoid rounding
    out[EE + e] = (z > -0.40546510810816444f) ? 1.0f : 0.0f;
  }
}

// ---------------------------------------------------------------------------
// Dense branch, bf16 MFMA (tolerance 0.02): wave = 16-j tile, loop 16 i's.
// ---------------------------------------------------------------------------
__global__ __launch_bounds__(256, 2) void dense_mfma_kernel(
    const float* __restrict__ x, const float* __restrict__ pre,
    const short* __restrict__ Wt0, const float* __restrict__ W2,
    const float* __restrict__ b2, float* __restrict__ outP) {
  const int lane = threadIdx.x & 63;
  const int w = threadIdx.x >> 6;
  const int q = lane >> 4;
  const int c = lane & 15;
  const int j0 = blockIdx.x * 64 + w * 16;
  const int i0 = blockIdx.y * 16;

  // B fragments hoisted: [n-tile][k-chunk]
  short8 Bf[2][4];
#pragma unroll
  for (int n = 0; n < 2; ++n)
#pragma unroll
    for (int s = 0; s < 4; ++s)
      Bf[n][s] = *(const short8*)(Wt0 + (n * 16 + c) * 128 + s * 32 + q * 8);

  const float* xj = x + (size_t)(j0 + c) * FD;
  float jA[8], jB[8];
#pragma unroll
  for (int t = 0; t < 4; ++t) {
    jA[t] = xj[q * 8 + t];      jA[4 + t] = xj[q * 8 + 4 + t];
    jB[t] = xj[32 + q * 8 + t]; jB[4 + t] = xj[32 + q * 8 + 4 + t];
  }

  float pdA[4], pdB[4];
#pragma unroll
  for (int r = 0; r < 4; ++r) {
    pdA[r] = pre[NN * HD + (j0 + q * 4 + r) * HD + c];
    pdB[r] = pre[NN * HD + (j0 + q * 4 + r) * HD + 16 + c];
  }
  const float w2a = W2[c], w2b = W2[16 + c];
  const float b2v = b2[0];

  for (int i = i0; i < i0 + 16; ++i) {
    const float* xi = x + (size_t)i * FD;
    const float psa = pre[i * HD + c];
    const float psb = pre[i * HD + 16 + c];
    floatx4 acc0, acc1;
#pragma unroll
    for (int r = 0; r < 4; ++r) {
      acc0[r] = psa + pdA[r];
      acc1[r] = psb + pdB[r];
    }
    // half A (f [q*8,q*8+8)): chunks 0 (ad) and 2 (pr)
    {
      const floatx4 i0v = *(const floatx4*)(xi + q * 8);
      const floatx4 i1v = *(const floatx4*)(xi + q * 8 + 4);
      float ad[8], pr[8];
#pragma unroll
      for (int t = 0; t < 4; ++t) {
        ad[t] = fabsf(i0v[t] - jA[t]);         pr[t] = i0v[t] * jA[t];
        ad[4 + t] = fabsf(i1v[t] - jA[4 + t]); pr[4 + t] = i1v[t] * jA[4 + t];
      }
      const short8 fad = pack8(ad);
      const short8 fpr = pack8(pr);
      acc0 = __builtin_amdgcn_mfma_f32_16x16x32_bf16(fad, Bf[0][0], acc0, 0, 0, 0);
      acc1 = __builtin_amdgcn_mfma_f32_16x16x32_bf16(fad, Bf[1][0], acc1, 0, 0, 0);
      acc0 = __builtin_amdgcn_mfma_f32_16x16x32_bf16(fpr, Bf[0][2], acc0, 0, 0, 0);
      acc1 = __builtin_amdgcn_mfma_f32_16x16x32_bf16(fpr, Bf[1][2], acc1, 0, 0, 0);
    }
    // half B (f [32+q*8,32+q*8+8)): chunks 1 (ad) and 3 (pr)
    {
      const floatx4 i0v = *(const floatx4*)(xi + 32 + q * 8);
      const floatx4 i1v = *(const floatx4*)(xi + 32 + q * 8 + 4);
      float ad[8], pr[8];
#pragma unroll
      for (int t = 0; t < 4; ++t) {
        ad[t] = fabsf(i0v[t] - jB[t]);         pr[t] = i0v[t] * jB[t];
        ad[4 + t] = fabsf(i1v[t] - jB[4 + t]); pr[4 + t] = i1v[t] * jB[4 + t];
      }
      const short8 fad = pack8(ad);
      const short8 fpr = pack8(pr);
      acc0 = __builtin_amdgcn_mfma_f32_16x16x32_bf16(fad, Bf[0][1], acc0, 0, 0, 0);
      acc1 = __builtin_amdgcn_mfma_f32_16x16x32_bf16(fad, Bf[1][1], acc1, 0, 0, 0);
      acc0 = __builtin_amdgcn_mfma_f32_16x16x32_bf16(fpr, Bf[0][3], acc0, 0, 0, 0);
      acc1 = __builtin_amdgcn_mfma_f32_16x16x32_bf16(fpr, Bf[1][3], acc1, 0, 0, 0);
    }
    // epilogue
    float tr[4];
#pragma unroll
    for (int r = 0; r < 4; ++r) {
      tr[r] = fmaxf(acc0[r], 0.0f) * w2a;
      tr[r] = fmaf(fmaxf(acc1[r], 0.0f), w2b, tr[r]);
#pragma unroll
      for (int m = 1; m <= 8; m <<= 1) tr[r] += __shfl_xor(tr[r], m);
    }
    float zs = tr[0];
    zs = (c == 1) ? tr[1] : zs;
    zs = (c == 2) ? tr[2] : zs;
    zs = (c == 3) ? tr[3] : zs;
    if (c < 4) {
      outP[(size_t)i * NN + j0 + q * 4 + c] = sigmoid_fast(zs + b2v);
    }
  }
}

// ---------------------------------------------------------------------------
// Fallbacks (no-workspace path)
// ---------------------------------------------------------------------------
__device__ __forceinline__ float pair_logit_full(
    const float* __restrict__ xs, const float* __restrict__ xd,
    const float* __restrict__ W1, const float* __restrict__ b1,
    const float* __restrict__ W2, const float b2v) {
  float acc[HD];
#pragma unroll
  for (int h = 0; h < HD; ++h) acc[h] = b1[h];
#pragma unroll 1
  for (int f = 0; f < FD; ++f) {
    const float a = xs[f], b = xd[f];
    const float ad = fabsf(a - b), pr = a * b;
#pragma unroll
    for (int h = 0; h < HD; ++h) {
      float t0 = fmaf(a, W1[f * HD + h], acc[h]);
      t0 = fmaf(b, W1[(FD + f) * HD + h], t0);
      t0 = fmaf(ad, W1[(2 * FD + f) * HD + h], t0);
      acc[h] = fmaf(pr, W1[(3 * FD + f) * HD + h], t0);
    }
  }
  float z = b2v;
#pragma unroll
  for (int h = 0; h < HD; ++h) z = fmaf(fmaxf(acc[h], 0.0f), W2[h], z);
  return z;
}

__global__ __launch_bounds__(256) void edge_kernel_fb(
    const float* __restrict__ x, const int* __restrict__ eidx,
    const float* __restrict__ W1, const float* __restrict__ b1,
    const float* __restrict__ W2, const float* __restrict__ b2,
    float* __restrict__ out) {
  const int e = blockIdx.x * 256 + threadIdx.x;
  const bool is64 = (eidx[1] == 0) && (eidx[3] == 0) && (eidx[5] == 0);
  int s, d;
  if (is64) { s = eidx[2 * e]; d = eidx[2 * (EE + e)]; }
  else { s = eidx[e]; d = eidx[EE + e]; }
  const float z = pair_logit_full(x + (size_t)s * FD, x + (size_t)d * FD,
                                  W1, b1, W2, b2[0]);
  const float p = sigmoid_f(z);
  out[e] = p;
  out[EE + e] = (p > 0.4f) ? 1.0f : 0.0f;
}

__global__ __launch_bounds__(256) void dense_full_fb(
    const float* __restrict__ x, const float* __restrict__ W1,
    const float* __restrict__ b1, const float* __restrict__ W2,
    const float* __restrict__ b2, float* __restrict__ outP) {
  const int j = blockIdx.x * 64 + threadIdx.x % 64;
  const int i = blockIdx.y * 4 + threadIdx.x / 64;
  const float z = pair_logit_full(x + (size_t)i * FD, x + (size_t)j * FD,
                                  W1, b1, W2, b2[0]);
  outP[(size_t)i * NN + j] = sigmoid_f(z);
}

extern "C" void kernel_launch(void* const* d_in, const int* in_sizes, int n_in,
                              void* d_out, int out_size, void* d_ws, size_t ws_size,
                              hipStream_t stream) {
  const float* x  = (const float*)d_in[0];
  const int*  ei  = (const int*)d_in[1];
  const float* W1 = (const float*)d_in[3];
  const float* b1 = (const float*)d_in[4];
  const float* W2 = (const float*)d_in[5];
  const float* b2 = (const float*)d_in[6];
  float* out  = (float*)d_out;   // [0,EE) probs, [EE,2EE) actions
  float* outP = out + 2 * EE;    // [2EE, 2EE+NN*NN) P

  const size_t pre_bytes = (size_t)2 * NN * HD * sizeof(float);
  const size_t wt_elems = 32 * 128;
  const size_t need = pre_bytes + 3 * wt_elems * sizeof(short);
  if (ws_size >= need) {
    float* pre = (float*)d_ws;
    short* Wt0 = (short*)((char*)d_ws + pre_bytes);
    short* Wt1 = Wt0 + wt_elems;
    short* Wt2 = Wt1 + wt_elems;
    pre_kernel3<<<257, 256, 0, stream>>>(x, W1, b1, pre, Wt0, Wt1, Wt2);
    edge_mfma_kernel<<<1024, 256, 0, stream>>>(x, ei, pre, Wt0, Wt1, Wt2,
                                               W2, b2, out);
    dense_mfma_kernel<<<dim3(16, 64), 256, 0, stream>>>(x, pre, Wt0, W2, b2,
                                                        outP);
  } else {
    edge_kernel_fb<<<EE / 256, 256, 0, stream>>>(x, ei, W1, b1, W2, b2, out);
    dense_full_fb<<<dim3(NN / 64, NN / 4), 256, 0, stream>>>(
        x, W1, b1, W2, b2, outP);
  }
}